// Round 5
// baseline (1073.384 us; speedup 1.0000x reference)
//
#include <hip/hip_runtime.h>
#include <math.h>

#define D       256
#define KCODES  1024
#define NROWS   65536
#define BETA    0.25f
#define MARGIN  2e-4f
#define MAXSURV 7

typedef __attribute__((ext_vector_type(8))) short bf16x8;
typedef __attribute__((ext_vector_type(4))) float f32x4;

__device__ __forceinline__ unsigned int bf16_rne(float f) {
    unsigned int u = __float_as_uint(f);
    return (u + 0x7FFFu + ((u >> 16) & 1u)) >> 16;   // RNE bf16 (inputs are finite/normal)
}
__device__ __forceinline__ float bf16_back(unsigned int h) {
    return __uint_as_float(h << 16);
}
__device__ __forceinline__ f32x4 mfma16(bf16x8 a, bf16x8 b, f32x4 c) {
    return __builtin_amdgcn_mfma_f32_16x16x32_bf16(a, b, c, 0, 0, 0);
}

// ---------- split codebook into bf16 hi/lo: cs[k][0:256]=hi, [256:512]=lo; e2f exact ----------
__global__ __launch_bounds__(256) void split_cb_kernel(const float* __restrict__ cb,
                                                       ushort* __restrict__ cs,
                                                       float* __restrict__ e2f) {
    int code = blockIdx.x * 4 + (threadIdx.x >> 6);
    int lane = threadIdx.x & 63;
    float4 v = ((const float4*)(cb + (size_t)code * D))[lane];
    double s = (double)v.x * v.x + (double)v.y * v.y +
               (double)v.z * v.z + (double)v.w * v.w;
    unsigned int h0 = bf16_rne(v.x), h1 = bf16_rne(v.y), h2 = bf16_rne(v.z), h3 = bf16_rne(v.w);
    unsigned int l0 = bf16_rne(v.x - bf16_back(h0)), l1 = bf16_rne(v.y - bf16_back(h1));
    unsigned int l2 = bf16_rne(v.z - bf16_back(h2)), l3 = bf16_rne(v.w - bf16_back(h3));
    ushort* ph = cs + (size_t)code * 512 + lane * 4;
    ph[0] = (ushort)h0; ph[1] = (ushort)h1; ph[2] = (ushort)h2; ph[3] = (ushort)h3;
    ushort* pl = ph + 256;
    pl[0] = (ushort)l0; pl[1] = (ushort)l1; pl[2] = (ushort)l2; pl[3] = (ushort)l3;
    #pragma unroll
    for (int off = 32; off > 0; off >>= 1) s += __shfl_down(s, off, 64);
    if (lane == 0) e2f[code] = (float)s;
}

// ---------- MFMA screening: per-row survivors of argmin_k (e2[k] - 2 x.c_k); also x2f ----------
__global__ __launch_bounds__(256, 2) void screen_kernel(
    const float* __restrict__ x, const ushort* __restrict__ cs,
    const float* __restrict__ e2f, float* __restrict__ x2f,
    ushort* __restrict__ rowlist)
{
    __shared__ __attribute__((aligned(16))) ushort Bt[32 * 520];  // 32 codes x (512 + 8 pad)
    __shared__ float  mrg_d[128][32];
    __shared__ ushort mrg_k[128][32];

    const int tid  = threadIdx.x;
    const int wave = tid >> 6, lane = tid & 63;
    const int quad = lane >> 4, m = lane & 15;
    const int rowBase = blockIdx.x * 128;
    const int wrb = rowBase + wave * 32;       // this wave's 32 rows (2 M-tiles)

    // ---- build A fragments in registers from fp32 x; accumulate exact x2 ----
    bf16x8 af[2][16];                          // [Mtile][chunk]: 0-7 = hi, 8-15 = lo
    #pragma unroll
    for (int t = 0; t < 2; ++t) {
        const float* xr = x + (size_t)(wrb + t * 16 + m) * D;
        double s = 0.0;
        #pragma unroll
        for (int c = 0; c < 8; ++c) {
            float4 f0 = *(const float4*)&xr[c * 32 + quad * 8];
            float4 f1 = *(const float4*)&xr[c * 32 + quad * 8 + 4];
            s += (double)f0.x * f0.x + (double)f0.y * f0.y +
                 (double)f0.z * f0.z + (double)f0.w * f0.w;
            s += (double)f1.x * f1.x + (double)f1.y * f1.y +
                 (double)f1.z * f1.z + (double)f1.w * f1.w;
            float ff[8] = {f0.x, f0.y, f0.z, f0.w, f1.x, f1.y, f1.z, f1.w};
            #pragma unroll
            for (int j = 0; j < 8; ++j) {
                unsigned int h = bf16_rne(ff[j]);
                unsigned int l = bf16_rne(ff[j] - bf16_back(h));
                af[t][c][j]     = (short)h;
                af[t][c + 8][j] = (short)l;
            }
        }
        s += __shfl_xor(s, 16, 64);
        s += __shfl_xor(s, 32, 64);
        if (quad == 0) x2f[wrb + t * 16 + m] = (float)s;
    }

    // ---- top-2 per (Mtile,row-reg) over this lane's code class ----
    float    d1[2][4], d2[2][4];
    unsigned k1[2][4], k2[2][4];
    #pragma unroll
    for (int t = 0; t < 2; ++t)
        #pragma unroll
        for (int r = 0; r < 4; ++r) { d1[t][r] = 1e30f; d2[t][r] = 1e30f; k1[t][r] = 0; k2[t][r] = 0; }

    const int sc = tid & 31, sp = tid >> 5;    // staging: code 0..31, part 0..7
    for (int kt = 0; kt < KCODES / 32; ++kt) {
        // stage B tile (32 codes x 512 split-bf16) global->regs->LDS
        const ushort* src = cs + (size_t)(kt * 32 + sc) * 512 + sp * 64;
        bf16x8 stg[8];
        #pragma unroll
        for (int i = 0; i < 8; ++i) stg[i] = *(const bf16x8*)&src[i * 8];
        __syncthreads();                        // prior tile's reads done
        ushort* dst = Bt + sc * 520 + sp * 64;
        #pragma unroll
        for (int i = 0; i < 8; ++i) *(bf16x8*)&dst[i * 8] = stg[i];
        __syncthreads();                        // tile visible

        #pragma unroll
        for (int nt = 0; nt < 2; ++nt) {
            f32x4 acc0 = {0.f, 0.f, 0.f, 0.f};
            f32x4 acc1 = {0.f, 0.f, 0.f, 0.f};
            const ushort* bp = Bt + (nt * 16 + m) * 520 + quad * 8;
            #pragma unroll
            for (int c = 0; c < 8; ++c) {
                bf16x8 bh = *(const bf16x8*)&bp[c * 32];
                bf16x8 bl = *(const bf16x8*)&bp[c * 32 + 256];
                acc0 = mfma16(af[0][c],     bh, acc0);   // hi*hi
                acc1 = mfma16(af[1][c],     bh, acc1);
                acc0 = mfma16(af[0][c],     bl, acc0);   // hi*lo
                acc1 = mfma16(af[1][c],     bl, acc1);
                acc0 = mfma16(af[0][c + 8], bh, acc0);   // lo*hi
                acc1 = mfma16(af[1][c + 8], bh, acc1);
            }
            unsigned kcode = kt * 32 + nt * 16 + m;
            float e2 = e2f[kcode];
            #pragma unroll
            for (int t = 0; t < 2; ++t) {
                f32x4 acc = t ? acc1 : acc0;
                #pragma unroll
                for (int r = 0; r < 4; ++r) {
                    float d = fmaf(-2.f, acc[r], e2);
                    bool lt2 = d < d2[t][r];
                    bool lt1 = d < d1[t][r];
                    d2[t][r] = lt2 ? (lt1 ? d1[t][r] : d) : d2[t][r];
                    k2[t][r] = lt2 ? (lt1 ? k1[t][r] : kcode) : k2[t][r];
                    d1[t][r] = lt1 ? d : d1[t][r];
                    k1[t][r] = lt1 ? kcode : k1[t][r];
                }
            }
        }
    }

    // ---- per-row merge of 16 classes x top-2 ----
    __syncthreads();                            // Bt reads done (reuse-safety) & before mrg
    #pragma unroll
    for (int t = 0; t < 2; ++t)
        #pragma unroll
        for (int r = 0; r < 4; ++r) {
            int rowloc = wave * 32 + t * 16 + quad * 4 + r;
            mrg_d[rowloc][m * 2 + 0] = d1[t][r];
            mrg_k[rowloc][m * 2 + 0] = (ushort)k1[t][r];
            mrg_d[rowloc][m * 2 + 1] = d2[t][r];
            mrg_k[rowloc][m * 2 + 1] = (ushort)k2[t][r];
        }
    __syncthreads();
    if (tid < 128) {
        float dmin = 1e30f;
        #pragma unroll
        for (int j = 0; j < 32; ++j) dmin = fminf(dmin, mrg_d[tid][j]);
        float lim = dmin + MARGIN;
        ushort out[8] = {0, 0, 0, 0, 0, 0, 0, 0};
        int cnt = 0;
        for (int j = 0; j < 32; ++j) {
            if (mrg_d[tid][j] <= lim && cnt < MAXSURV) { out[1 + cnt] = mrg_k[tid][j]; ++cnt; }
        }
        out[0] = (ushort)cnt;
        *(bf16x8*)&rowlist[(size_t)(rowBase + tid) * 8] = *(bf16x8*)out;
    }
}

// ---------- exact rescore + gather + mse: one wave per row ----------
__global__ __launch_bounds__(256) void rescore_kernel(
    const float* __restrict__ x, const float* __restrict__ cb,
    const float* __restrict__ x2f, const float* __restrict__ e2f,
    const ushort* __restrict__ rowlist, float* __restrict__ out_idxf,
    unsigned int* __restrict__ counts, float* __restrict__ y,
    float* __restrict__ msesum)
{
    int row  = blockIdx.x * 4 + (threadIdx.x >> 6);
    int lane = threadIdx.x & 63;
    const ushort* lst = rowlist + (size_t)row * 8;
    int cnt = lst[0];
    float x2 = x2f[row];
    float4 xv = ((const float4*)(x + (size_t)row * D))[lane];

    float bestd = 1e30f;
    int   bestk = 0;
    for (int s = 0; s < cnt; ++s) {
        int k = lst[1 + s];
        float4 cv = ((const float4*)(cb + (size_t)k * D))[lane];
        double p = (double)xv.x * cv.x + (double)xv.y * cv.y +
                   (double)xv.z * cv.z + (double)xv.w * cv.w;
        #pragma unroll
        for (int off = 32; off > 0; off >>= 1) p += __shfl_down(p, off, 64);
        float simf = (float)p;                  // correctly-rounded f32 sim (lane 0 exact)
        float tt   = x2 + e2f[k];               // fl32(x2+e2)
        float dq   = tt - 2.0f * simf;          // reference comparator
        if (dq < bestd || (dq == bestd && k < bestk)) { bestd = dq; bestk = k; }
    }
    int bk = __shfl(bestk, 0, 64);              // lane 0 had the exact sums
    if (lane == 0) {
        out_idxf[row] = (float)bk;
        atomicAdd(&counts[bk], 1u);
    }
    // gather + y + mse
    float4 q = ((const float4*)(cb + (size_t)bk * D))[lane];
    float4 dv;
    dv.x = q.x - xv.x; dv.y = q.y - xv.y; dv.z = q.z - xv.z; dv.w = q.w - xv.w;
    float4 yv;
    yv.x = xv.x + dv.x; yv.y = xv.y + dv.y; yv.z = xv.z + dv.z; yv.w = xv.w + dv.w;
    ((float4*)(y + (size_t)row * D))[lane] = yv;
    float s = dv.x * dv.x + dv.y * dv.y + dv.z * dv.z + dv.w * dv.w;
    #pragma unroll
    for (int off = 32; off > 0; off >>= 1) s += __shfl_down(s, off, 64);
    if (lane == 0) atomicAdd(msesum, s);
}

// ---------- final scalars ----------
__global__ __launch_bounds__(1024) void stats_kernel(
    const unsigned int* __restrict__ counts, const float* __restrict__ msesum,
    float* __restrict__ outs)
{
    int t = threadIdx.x;
    float p = (float)counts[t] * (1.0f / 65536.0f);
    float h = -p * log2f(p + 1e-10f);
    float u = (p > 0.f) ? 1.f : 0.f;
    #pragma unroll
    for (int off = 32; off > 0; off >>= 1) {
        h += __shfl_down(h, off, 64);
        u += __shfl_down(u, off, 64);
    }
    __shared__ float hs[16], us[16];
    int lane = t & 63, w = t >> 6;
    if (lane == 0) { hs[w] = h; us[w] = u; }
    __syncthreads();
    if (t == 0) {
        float H = 0.f, U = 0.f;
        #pragma unroll
        for (int i = 0; i < 16; ++i) { H += hs[i]; U += us[i]; }
        float m = *msesum * (1.0f / 16777216.0f);
        float loss = BETA * m + m;
        float perp = expf(H * 0.69314718055994530942f);
        outs[0] = loss;
        outs[1] = perp;
        outs[2] = U * (1.0f / 1024.0f);
        outs[3] = H;
    }
}

extern "C" void kernel_launch(void* const* d_in, const int* in_sizes, int n_in,
                              void* d_out, int out_size, void* d_ws, size_t ws_size,
                              hipStream_t stream) {
    const float* x  = (const float*)d_in[0];   // [65536, 256]
    const float* cb = (const float*)d_in[1];   // [1024, 256]
    float* out      = (float*)d_out;

    float* y        = out;                      // 16,777,216
    float* out_idxf = out + 16777216;           // 65,536
    float* outs     = out + 16777216 + 65536;   // loss, perp, usage, H

    // ws layout (bytes):
    // [0       .. 262143]  x2f (65536 f32)
    // [262144  .. 266239]  e2f (1024 f32)
    // [266240  .. 270335]  counts (1024 u32)
    // [270336  .. 270339]  msesum (f32)
    // [270400  .. 1318975] rowlist (65536 rows x 8 ushort)
    // [1318976 .. 2367551] cs (1024 x 512 ushort, bf16 hi|lo)
    float*        x2f     = (float*)d_ws;
    float*        e2f     = (float*)((char*)d_ws + 262144);
    unsigned int* counts  = (unsigned int*)((char*)d_ws + 266240);
    float*        msesum  = (float*)((char*)d_ws + 270336);
    ushort*       rowlist = (ushort*)((char*)d_ws + 270400);
    ushort*       cs      = (ushort*)((char*)d_ws + 1318976);

    hipMemsetAsync((char*)d_ws + 266240, 0, 4100, stream);  // counts + msesum
    split_cb_kernel<<<KCODES / 4, 256, 0, stream>>>(cb, cs, e2f);
    screen_kernel<<<NROWS / 128, 256, 0, stream>>>(x, cs, e2f, x2f, rowlist);
    rescore_kernel<<<NROWS / 4, 256, 0, stream>>>(x, cb, x2f, e2f, rowlist,
                                                  out_idxf, counts, y, msesum);
    stats_kernel<<<1, 1024, 0, stream>>>(counts, msesum, outs);
}

// Round 6
// 274.409 us; speedup vs baseline: 3.9116x; 3.9116x over previous
//
#include <hip/hip_runtime.h>
#include <math.h>

#define D       256
#define KCODES  1024
#define NROWS   65536
#define BETA    0.25f
#define MARGIN  2e-4f
#define MAXSURV 7

typedef __attribute__((ext_vector_type(8))) short bf16x8;
typedef __attribute__((ext_vector_type(4))) float f32x4;

__device__ __forceinline__ unsigned int bf16_rne(float f) {
    unsigned int u = __float_as_uint(f);
    return (u + 0x7FFFu + ((u >> 16) & 1u)) >> 16;   // RNE bf16 (inputs are finite/normal)
}
__device__ __forceinline__ float bf16_back(unsigned int h) {
    return __uint_as_float(h << 16);
}
__device__ __forceinline__ f32x4 mfma16(bf16x8 a, bf16x8 b, f32x4 c) {
    return __builtin_amdgcn_mfma_f32_16x16x32_bf16(a, b, c, 0, 0, 0);
}

// ---------- split codebook into bf16 hi/lo: cs[k][0:256]=hi, [256:512]=lo; e2f exact ----------
__global__ __launch_bounds__(256) void split_cb_kernel(const float* __restrict__ cb,
                                                       ushort* __restrict__ cs,
                                                       float* __restrict__ e2f) {
    int code = blockIdx.x * 4 + (threadIdx.x >> 6);
    int lane = threadIdx.x & 63;
    float4 v = ((const float4*)(cb + (size_t)code * D))[lane];
    double s = (double)v.x * v.x + (double)v.y * v.y +
               (double)v.z * v.z + (double)v.w * v.w;
    unsigned int h0 = bf16_rne(v.x), h1 = bf16_rne(v.y), h2 = bf16_rne(v.z), h3 = bf16_rne(v.w);
    unsigned int l0 = bf16_rne(v.x - bf16_back(h0)), l1 = bf16_rne(v.y - bf16_back(h1));
    unsigned int l2 = bf16_rne(v.z - bf16_back(h2)), l3 = bf16_rne(v.w - bf16_back(h3));
    ushort* ph = cs + (size_t)code * 512 + lane * 4;
    ph[0] = (ushort)h0; ph[1] = (ushort)h1; ph[2] = (ushort)h2; ph[3] = (ushort)h3;
    ushort* pl = ph + 256;
    pl[0] = (ushort)l0; pl[1] = (ushort)l1; pl[2] = (ushort)l2; pl[3] = (ushort)l3;
    #pragma unroll
    for (int off = 32; off > 0; off >>= 1) s += __shfl_down(s, off, 64);
    if (lane == 0) e2f[code] = (float)s;
}

// ---------- MFMA screening: per-row survivors of argmin_k (e2[k] - 2 x.c_k); also x2f ----------
__global__ __launch_bounds__(256, 2) void screen_kernel(
    const float* __restrict__ x, const ushort* __restrict__ cs,
    const float* __restrict__ e2f, float* __restrict__ x2f,
    ushort* __restrict__ rowlist)
{
    __shared__ __attribute__((aligned(16))) ushort Bt[32 * 520];  // 32 codes x (512 + 8 pad)
    __shared__ float  mrg_d[128][32];
    __shared__ ushort mrg_k[128][32];

    const int tid  = threadIdx.x;
    const int wave = tid >> 6, lane = tid & 63;
    const int quad = lane >> 4, m = lane & 15;
    const int rowBase = blockIdx.x * 128;
    const int wrb = rowBase + wave * 32;       // this wave's 32 rows (2 M-tiles)

    // ---- build A fragments in registers from fp32 x; accumulate exact x2 ----
    bf16x8 af[2][16];                          // [Mtile][chunk]: 0-7 = hi, 8-15 = lo
    #pragma unroll
    for (int t = 0; t < 2; ++t) {
        const float* xr = x + (size_t)(wrb + t * 16 + m) * D;
        double s = 0.0;
        #pragma unroll
        for (int c = 0; c < 8; ++c) {
            float4 f0 = *(const float4*)&xr[c * 32 + quad * 8];
            float4 f1 = *(const float4*)&xr[c * 32 + quad * 8 + 4];
            s += (double)f0.x * f0.x + (double)f0.y * f0.y +
                 (double)f0.z * f0.z + (double)f0.w * f0.w;
            s += (double)f1.x * f1.x + (double)f1.y * f1.y +
                 (double)f1.z * f1.z + (double)f1.w * f1.w;
            float ff[8] = {f0.x, f0.y, f0.z, f0.w, f1.x, f1.y, f1.z, f1.w};
            #pragma unroll
            for (int j = 0; j < 8; ++j) {
                unsigned int h = bf16_rne(ff[j]);
                unsigned int l = bf16_rne(ff[j] - bf16_back(h));
                af[t][c][j]     = (short)h;
                af[t][c + 8][j] = (short)l;
            }
        }
        s += __shfl_xor(s, 16, 64);
        s += __shfl_xor(s, 32, 64);
        if (quad == 0) x2f[wrb + t * 16 + m] = (float)s;
    }

    // ---- top-2 per (Mtile,row-reg) over this lane's code class ----
    float    d1[2][4], d2[2][4];
    unsigned k1[2][4], k2[2][4];
    #pragma unroll
    for (int t = 0; t < 2; ++t)
        #pragma unroll
        for (int r = 0; r < 4; ++r) { d1[t][r] = 1e30f; d2[t][r] = 1e30f; k1[t][r] = 0; k2[t][r] = 0; }

    const int sc = tid & 31, sp = tid >> 5;    // staging: code 0..31, part 0..7
    for (int kt = 0; kt < KCODES / 32; ++kt) {
        // stage B tile (32 codes x 512 split-bf16) global->regs->LDS
        const ushort* src = cs + (size_t)(kt * 32 + sc) * 512 + sp * 64;
        bf16x8 stg[8];
        #pragma unroll
        for (int i = 0; i < 8; ++i) stg[i] = *(const bf16x8*)&src[i * 8];
        __syncthreads();                        // prior tile's reads done
        ushort* dst = Bt + sc * 520 + sp * 64;
        #pragma unroll
        for (int i = 0; i < 8; ++i) *(bf16x8*)&dst[i * 8] = stg[i];
        __syncthreads();                        // tile visible

        #pragma unroll
        for (int nt = 0; nt < 2; ++nt) {
            f32x4 acc0 = {0.f, 0.f, 0.f, 0.f};
            f32x4 acc1 = {0.f, 0.f, 0.f, 0.f};
            const ushort* bp = Bt + (nt * 16 + m) * 520 + quad * 8;
            #pragma unroll
            for (int c = 0; c < 8; ++c) {
                bf16x8 bh = *(const bf16x8*)&bp[c * 32];
                bf16x8 bl = *(const bf16x8*)&bp[c * 32 + 256];
                acc0 = mfma16(af[0][c],     bh, acc0);   // hi*hi
                acc1 = mfma16(af[1][c],     bh, acc1);
                acc0 = mfma16(af[0][c],     bl, acc0);   // hi*lo
                acc1 = mfma16(af[1][c],     bl, acc1);
                acc0 = mfma16(af[0][c + 8], bh, acc0);   // lo*hi
                acc1 = mfma16(af[1][c + 8], bh, acc1);
            }
            unsigned kcode = kt * 32 + nt * 16 + m;
            float e2 = e2f[kcode];
            #pragma unroll
            for (int t = 0; t < 2; ++t) {
                f32x4 acc = t ? acc1 : acc0;
                #pragma unroll
                for (int r = 0; r < 4; ++r) {
                    float d = fmaf(-2.f, acc[r], e2);
                    bool lt2 = d < d2[t][r];
                    bool lt1 = d < d1[t][r];
                    d2[t][r] = lt2 ? (lt1 ? d1[t][r] : d) : d2[t][r];
                    k2[t][r] = lt2 ? (lt1 ? k1[t][r] : kcode) : k2[t][r];
                    d1[t][r] = lt1 ? d : d1[t][r];
                    k1[t][r] = lt1 ? kcode : k1[t][r];
                }
            }
        }
    }

    // ---- per-row merge of 16 classes x top-2 ----
    __syncthreads();                            // Bt reads done & before mrg reuse
    #pragma unroll
    for (int t = 0; t < 2; ++t)
        #pragma unroll
        for (int r = 0; r < 4; ++r) {
            int rowloc = wave * 32 + t * 16 + quad * 4 + r;
            mrg_d[rowloc][m * 2 + 0] = d1[t][r];
            mrg_k[rowloc][m * 2 + 0] = (ushort)k1[t][r];
            mrg_d[rowloc][m * 2 + 1] = d2[t][r];
            mrg_k[rowloc][m * 2 + 1] = (ushort)k2[t][r];
        }
    __syncthreads();
    if (tid < 128) {
        float dmin = 1e30f;
        #pragma unroll
        for (int j = 0; j < 32; ++j) dmin = fminf(dmin, mrg_d[tid][j]);
        float lim = dmin + MARGIN;
        ushort out[8] = {0, 0, 0, 0, 0, 0, 0, 0};
        int cnt = 0;
        for (int j = 0; j < 32; ++j) {
            if (mrg_d[tid][j] <= lim && cnt < MAXSURV) { out[1 + cnt] = mrg_k[tid][j]; ++cnt; }
        }
        out[0] = (ushort)cnt;
        *(bf16x8*)&rowlist[(size_t)(rowBase + tid) * 8] = *(bf16x8*)out;
    }
}

// ---------- exact rescore + gather + mse partial: one wave per row, NO global atomic on mse ----------
__global__ __launch_bounds__(256) void rescore_kernel(
    const float* __restrict__ x, const float* __restrict__ cb,
    const float* __restrict__ x2f, const float* __restrict__ e2f,
    const ushort* __restrict__ rowlist, float* __restrict__ out_idxf,
    unsigned int* __restrict__ counts, float* __restrict__ y,
    float* __restrict__ msepart)
{
    int row  = blockIdx.x * 4 + (threadIdx.x >> 6);
    int lane = threadIdx.x & 63;
    const ushort* lst = rowlist + (size_t)row * 8;
    int cnt = lst[0];
    float x2 = x2f[row];
    float4 xv = ((const float4*)(x + (size_t)row * D))[lane];

    float bestd = 1e30f;
    int   bestk = 0;
    for (int s = 0; s < cnt; ++s) {
        int k = lst[1 + s];
        float4 cv = ((const float4*)(cb + (size_t)k * D))[lane];
        double p = (double)xv.x * cv.x + (double)xv.y * cv.y +
                   (double)xv.z * cv.z + (double)xv.w * cv.w;
        #pragma unroll
        for (int off = 32; off > 0; off >>= 1) p += __shfl_down(p, off, 64);
        float simf = (float)p;                  // correctly-rounded f32 sim (lane 0 exact)
        float tt   = x2 + e2f[k];               // fl32(x2+e2)
        float dq   = tt - 2.0f * simf;          // reference comparator
        if (dq < bestd || (dq == bestd && k < bestk)) { bestd = dq; bestk = k; }
    }
    int bk = __shfl(bestk, 0, 64);              // lane 0 had the exact sums
    if (lane == 0) {
        out_idxf[row] = (float)bk;
        atomicAdd(&counts[bk], 1u);             // 1024 distinct addresses -> low contention
    }
    // gather + y + mse partial
    float4 q = ((const float4*)(cb + (size_t)bk * D))[lane];
    float4 dv;
    dv.x = q.x - xv.x; dv.y = q.y - xv.y; dv.z = q.z - xv.z; dv.w = q.w - xv.w;
    float4 yv;
    yv.x = xv.x + dv.x; yv.y = xv.y + dv.y; yv.z = xv.z + dv.z; yv.w = xv.w + dv.w;
    ((float4*)(y + (size_t)row * D))[lane] = yv;
    float s = dv.x * dv.x + dv.y * dv.y + dv.z * dv.z + dv.w * dv.w;
    #pragma unroll
    for (int off = 32; off > 0; off >>= 1) s += __shfl_down(s, off, 64);
    if (lane == 0) msepart[row] = s;            // plain store, no atomic
}

// ---------- final scalars: reduce msepart + counts -> loss, perplexity, usage, H ----------
__global__ __launch_bounds__(1024) void stats_kernel(
    const unsigned int* __restrict__ counts, const float* __restrict__ msepart,
    float* __restrict__ outs)
{
    int t = threadIdx.x;
    // mse partial reduction: 64 coalesced strided reads per thread
    float ms = 0.f;
    #pragma unroll
    for (int j = 0; j < 64; ++j) ms += msepart[t + 1024 * j];

    float p = (float)counts[t] * (1.0f / 65536.0f);
    float h = -p * log2f(p + 1e-10f);
    float u = (p > 0.f) ? 1.f : 0.f;
    #pragma unroll
    for (int off = 32; off > 0; off >>= 1) {
        h  += __shfl_down(h,  off, 64);
        u  += __shfl_down(u,  off, 64);
        ms += __shfl_down(ms, off, 64);
    }
    __shared__ float hs[16], us[16], mss[16];
    int lane = t & 63, w = t >> 6;
    if (lane == 0) { hs[w] = h; us[w] = u; mss[w] = ms; }
    __syncthreads();
    if (t == 0) {
        float H = 0.f, U = 0.f, M = 0.f;
        #pragma unroll
        for (int i = 0; i < 16; ++i) { H += hs[i]; U += us[i]; M += mss[i]; }
        float m = M * (1.0f / 16777216.0f);
        float loss = BETA * m + m;
        float perp = expf(H * 0.69314718055994530942f);
        outs[0] = loss;
        outs[1] = perp;
        outs[2] = U * (1.0f / 1024.0f);
        outs[3] = H;
    }
}

extern "C" void kernel_launch(void* const* d_in, const int* in_sizes, int n_in,
                              void* d_out, int out_size, void* d_ws, size_t ws_size,
                              hipStream_t stream) {
    const float* x  = (const float*)d_in[0];   // [65536, 256]
    const float* cb = (const float*)d_in[1];   // [1024, 256]
    float* out      = (float*)d_out;

    float* y        = out;                      // 16,777,216
    float* out_idxf = out + 16777216;           // 65,536
    float* outs     = out + 16777216 + 65536;   // loss, perp, usage, H

    // ws layout (bytes):
    // [0       .. 262143]  x2f (65536 f32)
    // [262144  .. 266239]  e2f (1024 f32)
    // [266240  .. 270335]  counts (1024 u32)
    // [270336  .. 270339]  (unused)
    // [270400  .. 1318975] rowlist (65536 rows x 8 ushort)
    // [1318976 .. 2367551] cs (1024 x 512 ushort, bf16 hi|lo)
    // [2367552 .. 2629695] msepart (65536 f32)
    float*        x2f     = (float*)d_ws;
    float*        e2f     = (float*)((char*)d_ws + 262144);
    unsigned int* counts  = (unsigned int*)((char*)d_ws + 266240);
    ushort*       rowlist = (ushort*)((char*)d_ws + 270400);
    ushort*       cs      = (ushort*)((char*)d_ws + 1318976);
    float*        msepart = (float*)((char*)d_ws + 2367552);

    hipMemsetAsync((char*)d_ws + 266240, 0, 4096, stream);  // counts
    split_cb_kernel<<<KCODES / 4, 256, 0, stream>>>(cb, cs, e2f);
    screen_kernel<<<NROWS / 128, 256, 0, stream>>>(x, cs, e2f, x2f, rowlist);
    rescore_kernel<<<NROWS / 4, 256, 0, stream>>>(x, cb, x2f, e2f, rowlist,
                                                  out_idxf, counts, y, msepart);
    stats_kernel<<<1, 1024, 0, stream>>>(counts, msepart, outs);
}